// Round 13
// baseline (446.871 us; speedup 1.0000x reference)
//
#include <hip/hip_runtime.h>

// B=8, N=2048, D=F=768. out = softmax((X Wq)(X Wk)^T) (X Wv), fp32 I/O.
// Identity: S[q][k] = sum_d X[q][d] * H[k][d],  H = X * M^T,  M = Wq Wk^T.
// ws: H = fp16(X M^T) [16384][768] | Vt = fp16(X Wv)^T [8][768][2048]
// d_out scratch: Mh fp16 @0 | WvT fp16 @2359296 | Xh fp16 @4194304.
// v17: attn sync-fabric restructure. Per iter: 2 barriers + 0 serial sections
//   (was 3 + 2). Every wave redundantly folds pm/psum for row=lane (8 scalar
//   LDS reads each, conflict-free); m_run/l_run live in per-lane REGISTERS
//   (identical duplicates across waves); per-row alpha/max/inv-denom reach the
//   16-rows-per-lane acc pattern via __shfl(x,row). S/PV phases byte-identical
//   to v10 (depth-8 rings). prep/proj byte-identical to v16 (428.4us total).

typedef __attribute__((ext_vector_type(8))) _Float16 half8;
typedef __attribute__((ext_vector_type(4))) _Float16 half4v;
typedef __attribute__((ext_vector_type(4))) float floatx4;

__device__ __forceinline__ _Float16 f2h(float f) { return (_Float16)f; }
#define MFMA16 __builtin_amdgcn_mfma_f32_16x16x32_f16

// ---------------- prep: cast_x U pack_wv U mm_small ----------------
__global__ __launch_bounds__(256) void prep_kernel(const float* __restrict__ X,
    const float* __restrict__ Wq, const float* __restrict__ Wk,
    const float* __restrict__ Wv, _Float16* __restrict__ Xh,
    _Float16* __restrict__ Mh, _Float16* __restrict__ WvT) {
  __shared__ _Float16 As[128][72];
  __shared__ _Float16 Bs[128][72];
  __shared__ float tileF[32][33];
  int id = blockIdx.x;
  int tid = threadIdx.x;
  if (id < 2048) {
    size_t idx = (size_t)id * 256 + tid;
    for (size_t o8 = idx; o8 < 1572864u; o8 += 524288u) {
      size_t o = o8 * 8;
      float4 a = *(const float4*)(X + o);
      float4 b = *(const float4*)(X + o + 4);
      *(half8*)(Xh + o) = (half8){f2h(a.x), f2h(a.y), f2h(a.z), f2h(a.w),
                                  f2h(b.x), f2h(b.y), f2h(b.z), f2h(b.w)};
    }
  } else if (id < 2624) {
    int pid = id - 2048;
    int k0 = (pid % 24) * 32, n0 = (pid / 24) * 32;
    int tx = tid & 31, ty = tid >> 5;
    for (int yy = ty; yy < 32; yy += 8)
      tileF[yy][tx] = Wv[(size_t)(k0 + yy) * 768 + n0 + tx];
    __syncthreads();
    for (int yy = ty; yy < 32; yy += 8)
      WvT[(size_t)(n0 + yy) * 768 + k0 + tx] = f2h(tileF[tx][yy]);
  } else {
    int pid = id - 2624;
    int bn = pid % 6, bm = pid / 6;
    int lane = tid & 63, wave = tid >> 6;
    int wm = wave >> 1, wn = wave & 1;
    int l15 = lane & 15, quad = lane >> 4;
    floatx4 acc[16];
    for (int i = 0; i < 16; i++) acc[i] = (floatx4){0.f, 0.f, 0.f, 0.f};
    for (int k0 = 0; k0 < 768; k0 += 64) {
      __syncthreads();
      for (int i = 0; i < 8; i++) {
        int f = i * 256 + tid;
        int row = f >> 4, c4 = (f & 15) << 2;
        float4 va = *(const float4*)(Wq + (size_t)(bm * 128 + row) * 768 + k0 + c4);
        *(half4v*)&As[row][c4] = (half4v){f2h(va.x), f2h(va.y), f2h(va.z), f2h(va.w)};
        float4 vb = *(const float4*)(Wk + (size_t)(bn * 128 + row) * 768 + k0 + c4);
        *(half4v*)&Bs[row][c4] = (half4v){f2h(vb.x), f2h(vb.y), f2h(vb.z), f2h(vb.w)};
      }
      __syncthreads();
      for (int kk = 0; kk < 2; kk++) {
        half8 a[4], b[4];
        for (int mt = 0; mt < 4; mt++) a[mt] = *(half8*)&As[wm * 64 + mt * 16 + l15][kk * 32 + quad * 8];
        for (int nt = 0; nt < 4; nt++) b[nt] = *(half8*)&Bs[wn * 64 + nt * 16 + l15][kk * 32 + quad * 8];
        for (int mt = 0; mt < 4; mt++)
          for (int nt = 0; nt < 4; nt++)
            acc[mt * 4 + nt] = MFMA16(a[mt], b[nt], acc[mt * 4 + nt], 0, 0, 0);
      }
    }
    for (int mt = 0; mt < 4; mt++)
      for (int nt = 0; nt < 4; nt++) {
        int e = bn * 128 + wn * 64 + nt * 16 + l15;
        for (int r = 0; r < 4; r++) {
          int d = bm * 128 + wm * 64 + mt * 16 + quad * 4 + r;
          Mh[(size_t)d * 768 + e] = f2h(acc[mt * 4 + nt][r]);
        }
      }
  }
}

// ---------------- fused proj: H (bn<6) and Vt (bn>=6), v14 structure ----------------
__global__ __launch_bounds__(256) void proj_kernel(const _Float16* __restrict__ Xh,
    const _Float16* __restrict__ Mh, const _Float16* __restrict__ WvT,
    _Float16* __restrict__ H, _Float16* __restrict__ Vt) {
  __shared__ _Float16 As[128][72];
  __shared__ _Float16 Bs[128][72];   // 36,864 B -> 4 blocks/CU
  int bnRaw = blockIdx.x, bm = blockIdx.y;
  int isV = bnRaw >= 6;
  int bn = isV ? bnRaw - 6 : bnRaw;
  const _Float16* Bsrc = isV ? WvT : Mh;
  int tid = threadIdx.x, lane = tid & 63, wave = tid >> 6;
  int wm = wave >> 1, wn = wave & 1;
  int l15 = lane & 15, quad = lane >> 4;
  floatx4 acc[16];
  for (int i = 0; i < 16; i++) acc[i] = (floatx4){0.f, 0.f, 0.f, 0.f};
  half8 ra[4], rb[4];
  #pragma unroll
  for (int i = 0; i < 4; i++) {
    int f = i * 256 + tid, row = f >> 3, c8 = (f & 7) << 3;
    ra[i] = *(const half8*)(Xh + (size_t)(bm * 128 + row) * 768 + c8);
    rb[i] = *(const half8*)(Bsrc + (size_t)(bn * 128 + row) * 768 + c8);
  }
  for (int t = 0; t < 12; t++) {
    #pragma unroll
    for (int i = 0; i < 4; i++) {
      int f = i * 256 + tid, row = f >> 3, c8 = (f & 7) << 3;
      *(half8*)&As[row][c8] = ra[i];
      *(half8*)&Bs[row][c8] = rb[i];
    }
    __syncthreads();   // buf ready
    if (t < 11) {      // issue next-tile loads; latency hides under the MFMA block
      int k0 = (t + 1) * 64;
      #pragma unroll
      for (int i = 0; i < 4; i++) {
        int f = i * 256 + tid, row = f >> 3, c8 = (f & 7) << 3;
        ra[i] = *(const half8*)(Xh + (size_t)(bm * 128 + row) * 768 + k0 + c8);
        rb[i] = *(const half8*)(Bsrc + (size_t)(bn * 128 + row) * 768 + k0 + c8);
      }
    }
    #pragma unroll
    for (int kk = 0; kk < 2; kk++) {
      half8 a[4], b[4];
      #pragma unroll
      for (int mt = 0; mt < 4; mt++) a[mt] = *(half8*)&As[wm * 64 + mt * 16 + l15][kk * 32 + quad * 8];
      #pragma unroll
      for (int nt = 0; nt < 4; nt++) b[nt] = *(half8*)&Bs[wn * 64 + nt * 16 + l15][kk * 32 + quad * 8];
      #pragma unroll
      for (int mt = 0; mt < 4; mt++)
        #pragma unroll
        for (int nt = 0; nt < 4; nt++)
          acc[mt * 4 + nt] = MFMA16(a[mt], b[nt], acc[mt * 4 + nt], 0, 0, 0);
    }
    __syncthreads();   // all reads of buf done before next write
  }
  if (!isV) {
    for (int mt = 0; mt < 4; mt++)
      for (int nt = 0; nt < 4; nt++) {
        int col = bn * 128 + wn * 64 + nt * 16 + l15;
        for (int r = 0; r < 4; r++) {
          int row = bm * 128 + wm * 64 + mt * 16 + quad * 4 + r;
          H[(size_t)row * 768 + col] = f2h(acc[mt * 4 + nt][r]);
        }
      }
  } else {
    for (int mt = 0; mt < 4; mt++)
      for (int nt = 0; nt < 4; nt++) {
        int d = bn * 128 + wn * 64 + nt * 16 + l15;
        int tok0 = bm * 128 + wm * 64 + mt * 16 + quad * 4;
        int bb = tok0 >> 11, ntok = tok0 & 2047;
        half4v p;
        for (int r = 0; r < 4; r++) p[r] = f2h(acc[mt * 4 + nt][r]);
        *(half4v*)(Vt + (size_t)(bb * 768 + d) * 2048 + ntok) = p;
      }
  }
}

// ---------------- flash attention v17: 2 barriers/iter, register softmax state ----------------
__global__ __launch_bounds__(512, 2) void attn_kernel(const _Float16* __restrict__ H,
    const float* __restrict__ X, const _Float16* __restrict__ Vt, float* __restrict__ out) {
  __shared__ _Float16 Qs[64][776];   // 99,328 B
  __shared__ _Float16 Pl[64][136];   // 17,408 B
  __shared__ float pm[8][64];        //  2,048 B
  __shared__ float psum[8][64];      //  2,048 B
  // 120,832 B -> 1 block/CU. No m_run/l_run/gmax/galpha LDS (register-resident).

  int id = blockIdx.x;
  int b = id & 7;            // batch -> XCD
  int q0 = (id >> 3) * 64;   // 32 q-tiles per batch
  int tid = threadIdx.x;
  int lane = tid & 63, w = tid >> 6;   // w in 0..7
  int l15 = lane & 15, quad = lane >> 4;

  // per-lane softmax state for row = lane; every wave keeps an identical copy
  // (deterministic: all fold the same pm/psum LDS data).
  float m_run_r = -1e30f;
  float l_run_r = 0.f;

  floatx4 accO[24];   // [nt][ss]: 6 d-tiles x 4 q-subtiles; wave owns d [w*96,+96)
  for (int i = 0; i < 24; i++) accO[i] = (floatx4){0.f, 0.f, 0.f, 0.f};

  const float*    Xq    = X + (size_t)(b * 2048 + q0) * 768;
  const _Float16* Hbase = H + (size_t)(b * 2048) * 768;
  const _Float16* Vbase = Vt + (size_t)b * 768 * 2048;

  // stage queries: X fp32 -> Qs fp16 (64 x 768), 6144 half8 chunks / 512 thr
  for (int i = 0; i < 12; i++) {
    int f = i * 512 + tid;
    int row = f / 96, c8 = (f % 96) * 8;
    float4 a = *(const float4*)(Xq + (size_t)row * 768 + c8);
    float4 c = *(const float4*)(Xq + (size_t)row * 768 + c8 + 4);
    *(half8*)&Qs[row][c8] = (half8){f2h(a.x), f2h(a.y), f2h(a.z), f2h(a.w),
                                    f2h(c.x), f2h(c.y), f2h(c.z), f2h(c.w)};
  }
  __syncthreads();

  for (int m0 = 0; m0 < 2048; m0 += 128) {
    // ======== S = Q H^T : 64 q-rows x 128 keys; wave w: keys [w*16,+16) ========
    floatx4 sa[4];
    #pragma unroll
    for (int ss = 0; ss < 4; ss++) sa[ss] = (floatx4){0.f, 0.f, 0.f, 0.f};
    const _Float16* Kr = Hbase + (size_t)(m0 + w * 16 + l15) * 768 + quad * 8;
    half8 kpre[8];   // depth-8 ring
    #pragma unroll
    for (int i = 0; i < 8; i++) kpre[i] = *(const half8*)(Kr + i * 32);
    #pragma unroll
    for (int kb = 0; kb < 24; kb++) {
      half8 kcur = kpre[kb & 7];
      int nxt = (kb + 8 < 24) ? (kb + 8) * 32 : 0;
      kpre[kb & 7] = *(const half8*)(Kr + nxt);
      #pragma unroll
      for (int ss = 0; ss < 4; ss++) {
        half8 qa = *(half8*)&Qs[ss * 16 + l15][kb * 32 + quad * 8];
        sa[ss] = MFMA16(qa, kcur, sa[ss], 0, 0, 0);
      }
    }
    // hoist first PV V loads (wave owns d [w*96,+96)); in flight during softmax
    const _Float16* vb0 = Vbase + (size_t)(w * 96 + l15) * 2048 + m0 + quad * 8;
    half8 vpre[8];   // depth-8 ring
    #pragma unroll
    for (int i = 0; i < 8; i++) {
      int nks = i / 6, nnt = i % 6;
      vpre[i] = *(const half8*)(vb0 + (size_t)nnt * 16 * 2048 + nks * 32);
    }

    // ======== wave-local row max over this wave's 16 keys ========
    float mv[16];
    #pragma unroll
    for (int i = 0; i < 16; i++) mv[i] = sa[i >> 2][i & 3];
    #pragma unroll
    for (int mask = 1; mask <= 8; mask <<= 1)
      #pragma unroll
      for (int i = 0; i < 16; i++) mv[i] = fmaxf(mv[i], __shfl_xor(mv[i], mask));
    if (l15 == 0) {
      #pragma unroll
      for (int i = 0; i < 16; i++) pm[w][(i >> 2) * 16 + quad * 4 + (i & 3)] = mv[i];
    }
    __syncthreads();   // barrier A: pm visible

    // ======== every wave folds row = lane (redundant, no serial section) ========
    float mn_r = m_run_r;
    #pragma unroll
    for (int w2 = 0; w2 < 8; w2++) mn_r = fmaxf(mn_r, pm[w2][lane]);
    float alpha_r = __expf(m_run_r - mn_r);   // first tile: exp(-1e30)=0
    m_run_r = mn_r;
    // redistribute per-row max/alpha to the 16-rows-per-lane acc pattern
    float mn_i[16], al[16];
    #pragma unroll
    for (int i = 0; i < 16; i++) {
      int row = (i >> 2) * 16 + quad * 4 + (i & 3);
      mn_i[i] = __shfl(mn_r, row);
      al[i]   = __shfl(alpha_r, row);
    }
    // ======== exp in regs -> Pl (A-layout), row partial sums ========
    float pr[16];
    #pragma unroll
    for (int i = 0; i < 16; i++) {
      int row = (i >> 2) * 16 + quad * 4 + (i & 3);
      float p = __expf(sa[i >> 2][i & 3] - mn_i[i]);
      pr[i] = p;
      Pl[row][w * 16 + l15] = f2h(p);
    }
    #pragma unroll
    for (int mask = 1; mask <= 8; mask <<= 1)
      #pragma unroll
      for (int i = 0; i < 16; i++) pr[i] += __shfl_xor(pr[i], mask);
    if (l15 == 0) {
      #pragma unroll
      for (int i = 0; i < 16; i++) psum[w][(i >> 2) * 16 + quad * 4 + (i & 3)] = pr[i];
    }
    // rescale O while Pl/psum settle
    #pragma unroll
    for (int nt = 0; nt < 6; nt++)
      #pragma unroll
      for (int i = 0; i < 16; i++)
        accO[nt * 4 + (i >> 2)][i & 3] *= al[i];
    __syncthreads();   // barrier B: Pl + psum visible

    // fold l_run for row = lane (redundant per wave, register-resident)
    {
      float s = 0.f;
      #pragma unroll
      for (int w2 = 0; w2 < 8; w2++) s += psum[w2][lane];
      l_run_r = l_run_r * alpha_r + s;
    }
    // ======== O += P V : 128 keys, 6 d-tiles x 4 q-subtiles ========
    #pragma unroll
    for (int ks = 0; ks < 4; ks++) {
      half8 pa[4];
      #pragma unroll
      for (int ss = 0; ss < 4; ss++) pa[ss] = *(half8*)&Pl[ss * 16 + l15][ks * 32 + quad * 8];
      #pragma unroll
      for (int nt = 0; nt < 6; nt++) {
        int idx = ks * 6 + nt;
        half8 vcur = vpre[idx & 7];
        int nidx = idx + 8;
        int nks = (nidx < 24) ? nidx / 6 : 0;
        int nnt = (nidx < 24) ? nidx % 6 : 0;
        vpre[idx & 7] = *(const half8*)(vb0 + (size_t)nnt * 16 * 2048 + nks * 32);
        #pragma unroll
        for (int ss = 0; ss < 4; ss++)
          accO[nt * 4 + ss] = MFMA16(pa[ss], vcur, accO[nt * 4 + ss], 0, 0, 0);
      }
    }
  }
  // final normalization: per-row inv-denom via shuffle from the register copy
  float il[16];
  #pragma unroll
  for (int i = 0; i < 16; i++) {
    int row = (i >> 2) * 16 + quad * 4 + (i & 3);
    il[i] = 1.f / __shfl(l_run_r, row);
  }
  #pragma unroll
  for (int nt = 0; nt < 6; nt++)
    #pragma unroll
    for (int ss = 0; ss < 4; ss++) {
      int d = w * 96 + nt * 16 + l15;
      #pragma unroll
      for (int r = 0; r < 4; r++) {
        int row = q0 + ss * 16 + quad * 4 + r;
        out[(size_t)(b * 2048 + row) * 768 + d] = accO[nt * 4 + ss][r] * il[ss * 4 + r];
      }
    }
}

extern "C" void kernel_launch(void* const* d_in, const int* in_sizes, int n_in,
                              void* d_out, int out_size, void* d_ws, size_t ws_size,
                              hipStream_t stream) {
  (void)in_sizes; (void)n_in; (void)out_size; (void)ws_size;
  const float* X  = (const float*)d_in[0];
  const float* Wq = (const float*)d_in[1];
  const float* Wk = (const float*)d_in[2];
  const float* Wv = (const float*)d_in[3];
  float* out = (float*)d_out;

  char* ws = (char*)d_ws;
  _Float16* H  = (_Float16*)ws;                        // 25,165,824 B
  _Float16* Vt = (_Float16*)(ws + 25165824);           // 25,165,824 B

  // scratch in d_out, consumed before attn writes out:
  _Float16* Mh  = (_Float16*)d_out;                       // 1,179,648 B @ 0
  _Float16* WvT = (_Float16*)((char*)d_out + 2359296);    // 1,179,648 B
  _Float16* Xh  = (_Float16*)((char*)d_out + 4194304);    // 25,165,824 B (ends 29.4 MB)

  prep_kernel<<<2660, 256, 0, stream>>>(X, Wq, Wk, Wv, Xh, Mh, WvT);
  proj_kernel<<<dim3(12, 128), 256, 0, stream>>>(Xh, Mh, WvT, H, Vt);
  attn_kernel<<<256, 512, 0, stream>>>(H, X, Vt, out);
}